// Round 13
// baseline (27743.225 us; speedup 1.0000x reference)
//
#include <hip/hip_runtime.h>
#include <hip/hip_bf16.h>
#include <stdint.h>

typedef float f32x4 __attribute__((ext_vector_type(4)));
typedef short bf16x8 __attribute__((ext_vector_type(8)));

#define LDW 1024
#define BATCH_SH 20  // 1<<20 elements per 1024x1024 matrix
#define NBLK 256     // persistent grid: 1 block/CU (forced by 128KB LDS)
#define SCOPE __HIP_MEMORY_SCOPE_AGENT

__device__ __forceinline__ float b2f(__hip_bfloat16 h) { return __bfloat162float(h); }
__device__ __forceinline__ __hip_bfloat16 f2b(float f) { return __float2bfloat16(f); }

__device__ __forceinline__ void gload16(const void* g, void* l) {
  __builtin_amdgcn_global_load_lds((const __attribute__((address_space(1))) void*)g,
                                   (__attribute__((address_space(3))) void*)l,
                                   16, 0, 0);
}

// monotone-counter grid barrier (all NBLK blocks co-resident; device-scope
// atomics per G16 handle cross-XCD L2 non-coherence). cnt zeroed per launch.
__device__ __forceinline__ void grid_bar(int* cnt, int idx) {
  __syncthreads();
  if (threadIdx.x == 0) {
    __hip_atomic_fetch_add(cnt, 1, __ATOMIC_ACQ_REL, SCOPE);
    const int target = idx * NBLK;
    while (__hip_atomic_load(cnt, __ATOMIC_ACQUIRE, SCOPE) < target)
      __builtin_amdgcn_s_sleep(2);
  }
  __syncthreads();
}

__global__ void k_zero(int* p, int n) {
  if ((int)threadIdx.x < n) p[threadIdx.x] = 0;
}

// ---------------- one 256x256 split-bf16 GEMM tile (round-12 code verbatim) ----------------
// C = PA * PB^T over 3 K-segments (effective K=3072). 512 threads = 8 waves.
// mode 1 (SYM):  write splits at (i,j); mirror to (j,i) if tm!=tn.
// mode 2 (POLY): v = c2*C + c1*(eh+el) + c0*I; mirrored like mode 1.
// mode 3 (XUP):  if(oh) coalesced splits; if(oth) fused LDS-transpose splits;
//                if(of) fp32.

#define SEGPTRS(S)                                                                        \
  const int seg_ = (S) >> 4, k0_ = ((S) & 15) << 6;                                       \
  const __hip_bfloat16* pa_ = seg_ == 0 ? pa0 : seg_ == 1 ? pa1 : pa2;                    \
  const __hip_bfloat16* pb_ = seg_ == 0 ? pb0 : seg_ == 1 ? pb1 : pb2;

#define STAGE_GL(DB, S)                                                                   \
  {                                                                                       \
    SEGPTRS(S)                                                                            \
    char* lb_ = smem + (DB) * 65536;                                                      \
    _Pragma("unroll") for (int it_ = 0; it_ < 4; ++it_) {                                 \
      const int r_ = it_ * 64 + w * 8 + (l >> 3);                                         \
      const int kx_ = k0_ + (((l & 7) ^ (l >> 3)) << 3);                                  \
      gload16(pa_ + boff + (size_t)(rowA + r_) * LDW + kx_,                               \
              lb_ + (it_ * 64 + w * 8) * 128 + l * 16);                                   \
      gload16(pb_ + boff + (size_t)(rowB + r_) * LDW + kx_,                               \
              lb_ + 32768 + (it_ * 64 + w * 8) * 128 + l * 16);                           \
    }                                                                                     \
  }

#define MFMA_PHASE(KK, BASE)                                                              \
  {                                                                                       \
    bf16x8 av[8], bv[4];                                                                  \
    _Pragma("unroll") for (int mi_ = 0; mi_ < 8; ++mi_)                                   \
        av[mi_] = *reinterpret_cast<const bf16x8*>(smem + (BASE) + offA[KK][mi_]);        \
    _Pragma("unroll") for (int ni_ = 0; ni_ < 4; ++ni_)                                   \
        bv[ni_] = *reinterpret_cast<const bf16x8*>(smem + (BASE) + offB[KK][ni_]);        \
    __builtin_amdgcn_s_setprio(1);                                                        \
    _Pragma("unroll") for (int mi_ = 0; mi_ < 8; ++mi_)                                   \
        _Pragma("unroll") for (int ni_ = 0; ni_ < 4; ++ni_)                               \
            acc[mi_][ni_] = __builtin_amdgcn_mfma_f32_16x16x32_bf16(                      \
                av[mi_], bv[ni_], acc[mi_][ni_], 0, 0, 0);                                \
    __builtin_amdgcn_s_setprio(0);                                                        \
  }

__device__ __forceinline__ void gemm_tile(
    const int mode, char* smem, const int t, const size_t boff,
    const int tm, const int tn,
    const __hip_bfloat16* pa0, const __hip_bfloat16* pa1, const __hip_bfloat16* pa2,
    const __hip_bfloat16* pb0, const __hip_bfloat16* pb1, const __hip_bfloat16* pb2,
    __hip_bfloat16* oh, __hip_bfloat16* ol,
    __hip_bfloat16* oth, __hip_bfloat16* otl, float* of,
    const __hip_bfloat16* eh, const __hip_bfloat16* el,
    const float c0, const float c1, const float c2) {
  const int w = t >> 6, l = t & 63;
  const int wr = w >> 2, wc = w & 3;
  const int rowA = tm * 256, rowB = tn * 256;

  f32x4 acc[8][4];
#pragma unroll
  for (int i = 0; i < 8; ++i)
#pragma unroll
    for (int j = 0; j < 4; ++j) acc[i][j] = (f32x4){0.f, 0.f, 0.f, 0.f};

  int offA[2][8], offB[2][4];
#pragma unroll
  for (int kk = 0; kk < 2; ++kk) {
    const int g = kk * 4 + (l >> 4);
#pragma unroll
    for (int mi = 0; mi < 8; ++mi) {
      const int rA = wr * 128 + mi * 16 + (l & 15);
      offA[kk][mi] = rA * 128 + ((g ^ (rA & 7)) << 4);
    }
#pragma unroll
    for (int ni = 0; ni < 4; ++ni) {
      const int rB = wc * 64 + ni * 16 + (l & 15);
      offB[kk][ni] = 32768 + rB * 128 + ((g ^ (rB & 7)) << 4);
    }
  }

  STAGE_GL(0, 0);
  asm volatile("s_waitcnt vmcnt(0)" ::: "memory");
  __builtin_amdgcn_sched_barrier(0);
  __builtin_amdgcn_s_barrier();
  __builtin_amdgcn_sched_barrier(0);

  for (int s = 0; s < 48; ++s) {
    const int base = (s & 1) * 65536;
    if (s + 1 < 48) STAGE_GL((s & 1) ^ 1, s + 1);
    __builtin_amdgcn_sched_barrier(0);
    MFMA_PHASE(0, base);
    MFMA_PHASE(1, base);
    asm volatile("s_waitcnt vmcnt(0) lgkmcnt(0)" ::: "memory");
    __builtin_amdgcn_sched_barrier(0);
    __builtin_amdgcn_s_barrier();
    __builtin_amdgcn_sched_barrier(0);
  }

  const int r0 = tm * 256 + wr * 128 + ((l >> 4) << 2);
  const int cb = tn * 256 + wc * 64 + (l & 15);
#pragma unroll
  for (int mi = 0; mi < 8; ++mi) {
#pragma unroll
    for (int ni = 0; ni < 4; ++ni) {
      const int ccol = cb + ni * 16;
#pragma unroll
      for (int j = 0; j < 4; ++j) {
        const int rrow = r0 + mi * 16 + j;
        const size_t idx = boff + (size_t)rrow * LDW + ccol;
        float v = acc[mi][ni][j];
        if (mode == 2)
          v = c2 * v + c1 * (b2f(eh[idx]) + b2f(el[idx])) + (rrow == ccol ? c0 : 0.f);
        __hip_bfloat16 h = f2b(v);
        __hip_bfloat16 lo = f2b(v - b2f(h));
        if (mode == 3) {
          if (oh) { oh[idx] = h; ol[idx] = lo; }
          if (of) of[idx] = v;
        } else {
          oh[idx] = h; ol[idx] = lo;
          if (tm != tn) {
            const size_t tix = boff + (size_t)ccol * LDW + rrow;
            oth[tix] = h; otl[tix] = lo;
          }
        }
      }
    }
  }

  // mode 3 fused transpose (dead staging LDS = one 256x128 u32 half-tile)
  if (mode == 3 && oth) {
    unsigned* tlds = reinterpret_cast<unsigned*>(smem);
    unsigned short* pth = reinterpret_cast<unsigned short*>(oth);
    unsigned short* ptl = reinterpret_cast<unsigned short*>(otl);
#pragma unroll
    for (int h2 = 0; h2 < 2; ++h2) {
      __builtin_amdgcn_s_barrier();
      if ((wc >> 1) == h2) {
#pragma unroll
        for (int mi = 0; mi < 8; ++mi) {
#pragma unroll
          for (int ni = 0; ni < 4; ++ni) {
            const int cl = (wc & 1) * 64 + ni * 16 + (l & 15);
#pragma unroll
            for (int j = 0; j < 4; ++j) {
              const int rr = wr * 128 + ((l >> 4) << 2) + mi * 16 + j;
              const float v = acc[mi][ni][j];
              const __hip_bfloat16 hh = f2b(v);
              const __hip_bfloat16 lo = f2b(v - b2f(hh));
              const unsigned pk = (unsigned)(*(const unsigned short*)&hh) |
                                  ((unsigned)(*(const unsigned short*)&lo) << 16);
              tlds[rr * 128 + (cl ^ ((rr >> 1) & 31))] = pk;
            }
          }
        }
      }
      __builtin_amdgcn_s_barrier();
#pragma unroll
      for (int i = 0; i < 16; ++i) {
        const int trow = w * 16 + i;
        const size_t obase = boff + (size_t)(tn * 256 + h2 * 128 + trow) * LDW + tm * 256;
#pragma unroll
        for (int c = 0; c < 2; ++c) {
          const int e0 = (c * 64 + l) * 2;
          const int m = (e0 >> 1) & 31;
          const unsigned p0 = tlds[e0 * 128 + (trow ^ m)];
          const unsigned p1 = tlds[(e0 + 1) * 128 + (trow ^ m)];
          *reinterpret_cast<unsigned*>(pth + obase + e0) = (p0 & 0xffffu) | (p1 << 16);
          *reinterpret_cast<unsigned*>(ptl + obase + e0) = (p0 >> 16) | (p1 & 0xffff0000u);
        }
      }
    }
    __syncthreads();  // transpose reads done before next tile's LDS staging
  }
}

// ---------------- persistent mega-kernel: whole pipeline, 16 grid barriers ----------------
__global__ __launch_bounds__(512, 1) void k_mega(
    const float* __restrict__ xin, const float* __restrict__ coef,
    float* __restrict__ xout,
    __hip_bfloat16* P0h, __hip_bfloat16* P0l,
    __hip_bfloat16* P1h, __hip_bfloat16* P1l,
    __hip_bfloat16* P2h, __hip_bfloat16* P2l,
    __hip_bfloat16* XTh, __hip_bfloat16* XTl,
    float* __restrict__ partials, int* cnt, int* steal, const int CH) {
  __shared__ __align__(16) char smem[131072];
  __shared__ int jslot;
  const int t = threadIdx.x, bid = blockIdx.x;
  const int xcd = bid & 7, lid = bid >> 3;  // locality heuristic only
  const int bpx = CH >> 3;                  // batches per xcd-class
  int bar = 0;

  // ---- P0: Frobenius partials (CH*8 chunks per xcd-class, lid-strided) ----
  {
    const int per = CH * 8;
    float* red = reinterpret_cast<float*>(smem);
    for (int j = lid; j < per; j += 32) {
      const int f = xcd * per + j;
      const int b = f >> 6, ch = f & 63;
      const size_t base = ((size_t)b << BATCH_SH) + (size_t)ch * 16384;
      float s = 0.f;
#pragma unroll
      for (int i = 0; i < 8; ++i) {
        f32x4 v = *reinterpret_cast<const f32x4*>(xin + base + (size_t)(i * 512 + t) * 4);
        s += v[0] * v[0] + v[1] * v[1] + v[2] * v[2] + v[3] * v[3];
      }
#pragma unroll
      for (int off = 32; off; off >>= 1) s += __shfl_down(s, off);
      if ((t & 63) == 0) red[t >> 6] = s;
      __syncthreads();
      if (t == 0) {
        float tot = 0.f;
#pragma unroll
        for (int i = 0; i < 8; ++i) tot += red[i];
        partials[f] = tot;
      }
      __syncthreads();
    }
  }
  grid_bar(cnt, ++bar);

  // ---- P1: scale + split + transpose-split (CH*32 64x64-tiles per xcd-class) ----
  {
    const int per = CH * 32;
    float* tile = reinterpret_cast<float*>(smem);  // [64][65]
    const int lr0 = t >> 6, lc = t & 63;
    for (int j = lid; j < per; j += 32) {
      const int f = xcd * per + j;
      const int b = f >> 8, t256 = f & 255;
      const int tmm = t256 >> 4, tnn = t256 & 15;
      const size_t boff = (size_t)b << BATCH_SH;
      float q = partials[b * 64 + (t & 63)];
#pragma unroll
      for (int off = 32; off; off >>= 1) q += __shfl_down(q, off);
      q = __shfl(q, 0);
      const float sc = 1.1f / sqrtf(q);
#pragma unroll
      for (int p = 0; p < 8; ++p) {
        const int lr = p * 8 + lr0;
        const size_t idx = boff + (size_t)(tmm * 64 + lr) * LDW + tnn * 64 + lc;
        const float v = xin[idx] * sc;
        __hip_bfloat16 h = f2b(v);
        P0h[idx] = h;
        P0l[idx] = f2b(v - b2f(h));
        tile[lr * 65 + lc] = v;
      }
      __syncthreads();
#pragma unroll
      for (int p = 0; p < 8; ++p) {
        const int lr = p * 8 + lr0;
        const float v = tile[lc * 65 + lr];
        const size_t idx = boff + (size_t)(tnn * 64 + lr) * LDW + tmm * 64 + lc;
        __hip_bfloat16 h = f2b(v);
        XTh[idx] = h;
        XTl[idx] = f2b(v - b2f(h));
      }
      __syncthreads();
    }
  }
  grid_bar(cnt, ++bar);

  const float c0 = coef[0], c1 = coef[1], c2 = coef[2];

  for (int it = 0; it < 5; ++it) {
    const int rX = it % 3, rA = (it + 1) % 3, rB = (it + 2) % 3;
    __hip_bfloat16* Xh = rX == 0 ? P0h : rX == 1 ? P1h : P2h;
    __hip_bfloat16* Xl = rX == 0 ? P0l : rX == 1 ? P1l : P2l;
    __hip_bfloat16* Ah = rA == 0 ? P0h : rA == 1 ? P1h : P2h;
    __hip_bfloat16* Al = rA == 0 ? P0l : rA == 1 ? P1l : P2l;
    __hip_bfloat16* Bh = rB == 0 ? P0h : rB == 1 ? P1h : P2h;
    __hip_bfloat16* Bl = rB == 0 ? P0l : rB == 1 ? P1l : P2l;

    // ---- SYM: A = XT*XT^T, 10 upper tiles/batch, per-xcd work stealing ----
    {
      const int NT = (CH * 10) >> 3;
      int* ctr = steal + (it * 2) * 8 + xcd;
      for (;;) {
        if (t == 0) jslot = __hip_atomic_fetch_add(ctr, 1, __ATOMIC_RELAXED, SCOPE);
        __syncthreads();
        const int j = jslot;
        __syncthreads();
        if (j >= NT) break;
        const int bat = xcd * bpx + j / 10;
        const int tl = j - (j / 10) * 10;
        const int tmm = (tl < 4) ? 0 : (tl < 7) ? 1 : (tl < 9) ? 2 : 3;
        const int tnn = (tl < 4) ? tl : (tl < 7) ? (tl - 3) : (tl < 9) ? (tl - 5) : 3;
        gemm_tile(1, smem, t, (size_t)bat << BATCH_SH, tmm, tnn,
                  XTh, XTh, XTl, XTh, XTl, XTh,
                  Ah, Al, Ah, Al, nullptr, nullptr, nullptr, 0.f, 0.f, 0.f);
      }
    }
    grid_bar(cnt, ++bar);

    // ---- POLY: B = c2*A^2 + c1*A + c0*I, 10 upper tiles/batch, stealing ----
    {
      const int NT = (CH * 10) >> 3;
      int* ctr = steal + (it * 2 + 1) * 8 + xcd;
      for (;;) {
        if (t == 0) jslot = __hip_atomic_fetch_add(ctr, 1, __ATOMIC_RELAXED, SCOPE);
        __syncthreads();
        const int j = jslot;
        __syncthreads();
        if (j >= NT) break;
        const int bat = xcd * bpx + j / 10;
        const int tl = j - (j / 10) * 10;
        const int tmm = (tl < 4) ? 0 : (tl < 7) ? 1 : (tl < 9) ? 2 : 3;
        const int tnn = (tl < 4) ? tl : (tl < 7) ? (tl - 3) : (tl < 9) ? (tl - 5) : 3;
        gemm_tile(2, smem, t, (size_t)bat << BATCH_SH, tmm, tnn,
                  Ah, Ah, Al, Ah, Al, Ah,
                  Bh, Bl, Bh, Bl, nullptr, Ah, Al, c0, c1, c2);
      }
    }
    grid_bar(cnt, ++bar);

    // ---- XUP: X_next = X*B^T, 16 tiles/batch, static (exact fit) ----
    {
      const int NT = CH * 2;
      for (int j = lid; j < NT; j += 32) {
        const int bat = xcd * bpx + (j >> 4);
        const int t16 = j & 15;
        gemm_tile(3, smem, t, (size_t)bat << BATCH_SH, t16 >> 2, t16 & 3,
                  Xh, Xh, Xl, Bh, Bl, Bh,
                  (it < 4) ? Ah : nullptr, (it < 4) ? Al : nullptr,
                  (it < 4) ? XTh : nullptr, (it < 4) ? XTl : nullptr,
                  (it == 4) ? xout : nullptr, nullptr, nullptr, 0.f, 0.f, 0.f);
      }
    }
    if (it < 4) grid_bar(cnt, ++bar);
  }
}

extern "C" void kernel_launch(void* const* d_in, const int* in_sizes, int n_in,
                              void* d_out, int out_size, void* d_ws, size_t ws_size,
                              hipStream_t stream) {
  (void)in_sizes; (void)n_in; (void)out_size;
  const float* xin = (const float*)d_in[0];
  const float* coef = (const float*)d_in[1];
  float* xout = (float*)d_out;

  // ws: 8 bf16 buffers (4 pairs) x CH x 2MB + partials + sync area
  int CH = 64;
  while (CH > 8 && ((size_t)CH * 16u * 1024u * 1024u + 65536u) > ws_size) CH >>= 1;

  const size_t nE = (size_t)CH << BATCH_SH;
  __hip_bfloat16* P0h = (__hip_bfloat16*)d_ws;
  __hip_bfloat16* P0l = P0h + nE;
  __hip_bfloat16* P1h = P0l + nE;
  __hip_bfloat16* P1l = P1h + nE;
  __hip_bfloat16* P2h = P1l + nE;
  __hip_bfloat16* P2l = P2h + nE;
  __hip_bfloat16* XTh = P2l + nE;
  __hip_bfloat16* XTl = XTh + nE;
  float* partials = (float*)(XTl + nE);
  int* sync_area = (int*)(partials + (size_t)CH * 64);  // [0]=bar cnt, [1..80]=steal

  for (int c = 0; c < 64; c += CH) {
    const float* xi = xin + ((size_t)c << BATCH_SH);
    float* X = xout + ((size_t)c << BATCH_SH);
    k_zero<<<dim3(1), 128, 0, stream>>>(sync_area, 81);
    k_mega<<<dim3(NBLK), 512, 0, stream>>>(xi, coef, X,
                                           P0h, P0l, P1h, P1l, P2h, P2l, XTh, XTl,
                                           partials, sync_area, sync_area + 1, CH);
  }
}

// Round 14
// 7541.890 us; speedup vs baseline: 3.6786x; 3.6786x over previous
//
#include <hip/hip_runtime.h>
#include <hip/hip_bf16.h>
#include <stdint.h>

typedef float f32x4 __attribute__((ext_vector_type(4)));
typedef short bf16x8 __attribute__((ext_vector_type(8)));

#define LDW 1024
#define BATCH_SH 20  // 1<<20 elements per 1024x1024 matrix

__device__ __forceinline__ float b2f(__hip_bfloat16 h) { return __bfloat162float(h); }
__device__ __forceinline__ __hip_bfloat16 f2b(float f) { return __float2bfloat16(f); }

__device__ __forceinline__ void gload16(const void* g, void* l) {
  __builtin_amdgcn_global_load_lds((const __attribute__((address_space(1))) void*)g,
                                   (__attribute__((address_space(3))) void*)l,
                                   16, 0, 0);
}

// ---------------- Frobenius norm partials ----------------
__global__ void k_partial(const float* __restrict__ xin, float* __restrict__ partials) {
  const int b = blockIdx.y, ch = blockIdx.x, t = threadIdx.x;
  const size_t base = ((size_t)b << BATCH_SH) + (size_t)ch * 16384;
  float s = 0.f;
#pragma unroll
  for (int i = 0; i < 16; ++i) {
    f32x4 v = *reinterpret_cast<const f32x4*>(xin + base + (size_t)(i * 256 + t) * 4);
    s += v[0] * v[0] + v[1] * v[1] + v[2] * v[2] + v[3] * v[3];
  }
#pragma unroll
  for (int off = 32; off; off >>= 1) s += __shfl_down(s, off);
  __shared__ float red[4];
  if ((t & 63) == 0) red[t >> 6] = s;
  __syncthreads();
  if (t == 0) partials[b * 64 + ch] = red[0] + red[1] + red[2] + red[3];
}

// ---------------- scale + split + transpose-split (scale folded in) ----------------
__global__ void k_scalesplit(const float* __restrict__ xin, const float* __restrict__ partials,
                             __hip_bfloat16* __restrict__ Xh, __hip_bfloat16* __restrict__ Xl,
                             __hip_bfloat16* __restrict__ XTh, __hip_bfloat16* __restrict__ XTl) {
  __shared__ float tile[64][65];
  const int b = blockIdx.z, tm = blockIdx.y, tn = blockIdx.x;
  const size_t boff = (size_t)b << BATCH_SH;
  const int t = threadIdx.x, lr0 = t >> 6, lc = t & 63;
  float q = partials[b * 64 + (t & 63)];
#pragma unroll
  for (int off = 32; off; off >>= 1) q += __shfl_down(q, off);
  q = __shfl(q, 0);
  const float s = 1.1f / sqrtf(q);
#pragma unroll
  for (int p = 0; p < 16; ++p) {
    const int lr = p * 4 + lr0;
    const size_t idx = boff + (size_t)(tm * 64 + lr) * LDW + tn * 64 + lc;
    const float v = xin[idx] * s;
    __hip_bfloat16 h = f2b(v);
    Xh[idx] = h;
    Xl[idx] = f2b(v - b2f(h));
    tile[lr][lc] = v;
  }
  __syncthreads();
#pragma unroll
  for (int p = 0; p < 16; ++p) {
    const int lr = p * 4 + lr0;
    const float v = tile[lc][lr];
    const size_t idx = boff + (size_t)(tn * 64 + lr) * LDW + tm * 64 + lc;
    __hip_bfloat16 h = f2b(v);
    XTh[idx] = h;
    XTl[idx] = f2b(v - b2f(h));
  }
}

// ---------------- split-bf16 GEMM: C = PA * PB^T, 256x256 tile, BK=64 ----------------
// Effective K = 3072 (3 bf16 segments). 512 threads = 8 waves (2M x 4N).
// NEW (T4): depth-2 prefetch with COUNTED vmcnt — tile s+2 staged into the
// just-read buffer after a WAR barrier; end-of-step waits vmcnt(8) (tile s+1
// complete) so tile s+2's loads stay in flight ACROSS the barrier (~2 K-steps
// of latency cover). vmcnt(0) only in the 2-step tail. Staging image and all
// read offsets unchanged from round 12.
// MODE 1 (SYM):  C symmetric; 10 upper tiles; mirror-write when tm!=tn.
// MODE 2 (POLY): v = c2*C + c1*A + c0*I; mirrored like MODE 1.
// MODE 3 (XUP):  v = C; coalesced splits; fused LDS-transpose splits; fp32.

#define SEGPTRS(S)                                                                        \
  const int seg_ = (S) >> 4, k0_ = ((S) & 15) << 6;                                       \
  const __hip_bfloat16* pa_ = seg_ == 0 ? pa0 : seg_ == 1 ? pa1 : pa2;                    \
  const __hip_bfloat16* pb_ = seg_ == 0 ? pb0 : seg_ == 1 ? pb1 : pb2;

// lane l of wave w stages row r = it*64 + w*8 + (l>>3), global chunk ((l&7)^(l>>3)),
// into linear LDS slot (row base + l*16). Image: LDS[r][slot] = chunk slot^(r&7).
#define STAGE_GL(DB, S)                                                                   \
  {                                                                                       \
    SEGPTRS(S)                                                                            \
    char* lb_ = smem + (DB) * 65536;                                                      \
    _Pragma("unroll") for (int it_ = 0; it_ < 4; ++it_) {                                 \
      const int r_ = it_ * 64 + w * 8 + (l >> 3);                                         \
      const int kx_ = k0_ + (((l & 7) ^ (l >> 3)) << 3);                                  \
      gload16(pa_ + boff + (size_t)(rowA + r_) * LDW + kx_,                               \
              lb_ + (it_ * 64 + w * 8) * 128 + l * 16);                                   \
      gload16(pb_ + boff + (size_t)(rowB + r_) * LDW + kx_,                               \
              lb_ + 32768 + (it_ * 64 + w * 8) * 128 + l * 16);                           \
    }                                                                                     \
  }

#define MFMA_CL(AV, BV)                                                                   \
  __builtin_amdgcn_s_setprio(1);                                                          \
  _Pragma("unroll") for (int mi_ = 0; mi_ < 8; ++mi_)                                     \
      _Pragma("unroll") for (int ni_ = 0; ni_ < 4; ++ni_)                                 \
          acc[mi_][ni_] = __builtin_amdgcn_mfma_f32_16x16x32_bf16(                        \
              AV[mi_], BV[ni_], acc[mi_][ni_], 0, 0, 0);                                  \
  __builtin_amdgcn_s_setprio(0);

#define SCB() __builtin_amdgcn_sched_barrier(0)
#define BAR() __builtin_amdgcn_s_barrier()

template <int MODE>
__global__ __launch_bounds__(512, 2) void k_gemm(
    const __hip_bfloat16* __restrict__ pa0, const __hip_bfloat16* __restrict__ pa1,
    const __hip_bfloat16* __restrict__ pa2, const __hip_bfloat16* __restrict__ pb0,
    const __hip_bfloat16* __restrict__ pb1, const __hip_bfloat16* __restrict__ pb2,
    __hip_bfloat16* oh, __hip_bfloat16* ol,
    __hip_bfloat16* oth, __hip_bfloat16* otl,
    float* __restrict__ of,
    const __hip_bfloat16* __restrict__ eh, const __hip_bfloat16* __restrict__ el,
    const float* __restrict__ coef) {
  __shared__ __align__(16) char smem[131072];  // 2 bufs x (A 32KB + B 32KB)
  const int t = threadIdx.x;
  const int w = t >> 6, l = t & 63;
  const int wr = w >> 2, wc = w & 3;  // 2M x 4N wave grid

  // Fully-bijective XCD-aware swizzle (m204): works for any gridDim.x.
  const int nwg = gridDim.x, q = nwg >> 3, r8 = nwg & 7;
  const int xcd = blockIdx.x & 7, o = blockIdx.x >> 3;
  const int wgid = (xcd < r8 ? xcd * (q + 1) : r8 * (q + 1) + (xcd - r8) * q) + o;

  int bat, tm, tn;
  if constexpr (MODE == 3) {
    bat = wgid >> 4;
    const int tile = wgid & 15;
    tm = tile >> 2; tn = tile & 3;
  } else {
    bat = (int)((unsigned)wgid / 10u);
    const int tile = wgid - bat * 10;
    tm = (tile < 4) ? 0 : (tile < 7) ? 1 : (tile < 9) ? 2 : 3;
    tn = (tile < 4) ? tile : (tile < 7) ? (tile - 3) : (tile < 9) ? (tile - 5) : 3;
  }
  const size_t boff = (size_t)bat << BATCH_SH;
  const int rowA = tm * 256, rowB = tn * 256;

  f32x4 acc[8][4];
#pragma unroll
  for (int i = 0; i < 8; ++i)
#pragma unroll
    for (int j = 0; j < 4; ++j) acc[i][j] = (f32x4){0.f, 0.f, 0.f, 0.f};

  // MFMA fragment LDS byte offsets (within a buffer), XOR chunk swizzle
  int offA[2][8], offB[2][4];
#pragma unroll
  for (int kk = 0; kk < 2; ++kk) {
    const int g = kk * 4 + (l >> 4);
#pragma unroll
    for (int mi = 0; mi < 8; ++mi) {
      const int rA = wr * 128 + mi * 16 + (l & 15);
      offA[kk][mi] = rA * 128 + ((g ^ (rA & 7)) << 4);
    }
#pragma unroll
    for (int ni = 0; ni < 4; ++ni) {
      const int rB = wc * 64 + ni * 16 + (l & 15);
      offB[kk][ni] = 32768 + rB * 128 + ((g ^ (rB & 7)) << 4);
    }
  }

  // prologue: stage tiles 0 and 1 (16 loads in flight), wait tile 0 only
  STAGE_GL(0, 0);
  STAGE_GL(1, 1);
  asm volatile("s_waitcnt vmcnt(8)" ::: "memory");
  SCB();
  BAR();
  SCB();

  for (int s = 0; s < 48; ++s) {
    const int base = (s & 1) * 65536;
    bf16x8 av0[8], bv0[4], av1[8], bv1[4];
#pragma unroll
    for (int i = 0; i < 8; ++i)
      av0[i] = *reinterpret_cast<const bf16x8*>(smem + base + offA[0][i]);
#pragma unroll
    for (int i = 0; i < 4; ++i)
      bv0[i] = *reinterpret_cast<const bf16x8*>(smem + base + offB[0][i]);
    MFMA_CL(av0, bv0);  // compiler's counted lgkm covers av0/bv0; kk1 reads overlap
#pragma unroll
    for (int i = 0; i < 8; ++i)
      av1[i] = *reinterpret_cast<const bf16x8*>(smem + base + offA[1][i]);
#pragma unroll
    for (int i = 0; i < 4; ++i)
      bv1[i] = *reinterpret_cast<const bf16x8*>(smem + base + offB[1][i]);
    asm volatile("s_waitcnt lgkmcnt(0)" ::: "memory");  // all reads of buf done (regs)
    SCB();
    BAR();  // WAR: every wave finished reading buf[s&1]
    SCB();
    if (s + 2 < 48) STAGE_GL((s & 1), s + 2);  // into just-read buffer; stays in flight
    SCB();
    MFMA_CL(av1, bv1);
    if (s + 2 < 48) {
      asm volatile("s_waitcnt vmcnt(8)" ::: "memory");  // tile s+1 landed; s+2 in flight
    } else {
      asm volatile("s_waitcnt vmcnt(0)" ::: "memory");  // tail drain
    }
    SCB();
    BAR();
    SCB();
  }

  float c0 = 0.f, c1 = 0.f, c2 = 0.f;
  if constexpr (MODE == 2) { c0 = coef[0]; c1 = coef[1]; c2 = coef[2]; }
  const int r0 = tm * 256 + wr * 128 + ((l >> 4) << 2);
  const int cb = tn * 256 + wc * 64 + (l & 15);
#pragma unroll
  for (int mi = 0; mi < 8; ++mi) {
#pragma unroll
    for (int ni = 0; ni < 4; ++ni) {
      const int ccol = cb + ni * 16;
#pragma unroll
      for (int j = 0; j < 4; ++j) {
        const int rrow = r0 + mi * 16 + j;
        const size_t idx = boff + (size_t)rrow * LDW + ccol;
        float v = acc[mi][ni][j];
        if constexpr (MODE == 2)
          v = c2 * v + c1 * (b2f(eh[idx]) + b2f(el[idx])) + (rrow == ccol ? c0 : 0.f);
        __hip_bfloat16 h = f2b(v);
        __hip_bfloat16 lo = f2b(v - b2f(h));
        if constexpr (MODE == 3) {
          if (oh) { oh[idx] = h; ol[idx] = lo; }
          if (of) of[idx] = v;
        } else {
          oh[idx] = h; ol[idx] = lo;
          if (tm != tn) {
            const size_t tix = boff + (size_t)ccol * LDW + rrow;
            oth[tix] = h; otl[tix] = lo;
          }
        }
      }
    }
  }

  // ---- MODE 3 fused transpose: dead staging LDS = one 256x128 u32 half-tile ----
  if constexpr (MODE == 3) {
    if (oth) {
      unsigned* tlds = reinterpret_cast<unsigned*>(smem);
      unsigned short* pth = reinterpret_cast<unsigned short*>(oth);
      unsigned short* ptl = reinterpret_cast<unsigned short*>(otl);
#pragma unroll
      for (int h2 = 0; h2 < 2; ++h2) {
        __builtin_amdgcn_s_barrier();  // K-loop reads / previous half reads done
        if ((wc >> 1) == h2) {         // waves owning this 128-col half pack into LDS
#pragma unroll
          for (int mi = 0; mi < 8; ++mi) {
#pragma unroll
            for (int ni = 0; ni < 4; ++ni) {
              const int cl = (wc & 1) * 64 + ni * 16 + (l & 15);  // 0..127 in half
#pragma unroll
              for (int j = 0; j < 4; ++j) {
                const int rr = wr * 128 + ((l >> 4) << 2) + mi * 16 + j;  // 0..255
                const float v = acc[mi][ni][j];
                const __hip_bfloat16 hh = f2b(v);
                const __hip_bfloat16 lo = f2b(v - b2f(hh));
                const unsigned pk = (unsigned)(*(const unsigned short*)&hh) |
                                    ((unsigned)(*(const unsigned short*)&lo) << 16);
                tlds[rr * 128 + (cl ^ ((rr >> 1) & 31))] = pk;
              }
            }
          }
        }
        __builtin_amdgcn_s_barrier();
        // all 8 waves: emit 16 transposed rows each, u32-packed coalesced stores
#pragma unroll
        for (int i = 0; i < 16; ++i) {
          const int trow = w * 16 + i;  // 0..127 within this half
          const size_t obase =
              boff + (size_t)(tn * 256 + h2 * 128 + trow) * LDW + tm * 256;
#pragma unroll
          for (int c = 0; c < 2; ++c) {
            const int e0 = (c * 64 + l) * 2;  // even element index 0..254
            const int m = (e0 >> 1) & 31;     // same mask for e0 and e0+1
            const unsigned p0 = tlds[e0 * 128 + (trow ^ m)];
            const unsigned p1 = tlds[(e0 + 1) * 128 + (trow ^ m)];
            *reinterpret_cast<unsigned*>(pth + obase + e0) =
                (p0 & 0xffffu) | (p1 << 16);
            *reinterpret_cast<unsigned*>(ptl + obase + e0) =
                (p0 >> 16) | (p1 & 0xffff0000u);
          }
        }
      }
    }
  }
}

extern "C" void kernel_launch(void* const* d_in, const int* in_sizes, int n_in,
                              void* d_out, int out_size, void* d_ws, size_t ws_size,
                              hipStream_t stream) {
  (void)in_sizes; (void)n_in; (void)out_size;
  const float* xin = (const float*)d_in[0];
  const float* coef = (const float*)d_in[1];
  float* xout = (float*)d_out;

  // ws need: 8 bf16 buffers (4 pairs) x CH x 2MB = 16 MB/batch (+64KB slack)
  int CH = 64;
  while (CH > 1 && ((size_t)CH * 16u * 1024u * 1024u + 65536u) > ws_size) CH >>= 1;

  const size_t nE = (size_t)CH << BATCH_SH;
  __hip_bfloat16* P0h = (__hip_bfloat16*)d_ws;
  __hip_bfloat16* P0l = P0h + nE;
  __hip_bfloat16* P1h = P0l + nE;
  __hip_bfloat16* P1l = P1h + nE;
  __hip_bfloat16* P2h = P1l + nE;
  __hip_bfloat16* P2l = P2h + nE;
  __hip_bfloat16* XTh = P2l + nE;
  __hip_bfloat16* XTl = XTh + nE;
  float* partials = (float*)(XTl + nE);

  for (int c = 0; c < 64; c += CH) {
    const float* xi = xin + ((size_t)c << BATCH_SH);
    float* X = xout + ((size_t)c << BATCH_SH);  // final fp32 output only
    k_partial<<<dim3(64, CH), 256, 0, stream>>>(xi, partials);
    k_scalesplit<<<dim3(16, 16, CH), 256, 0, stream>>>(xi, partials, P0h, P0l, XTh, XTl);

    // rotating pairs: X, A, B  (X_next reuses the dead A pair each iteration)
    __hip_bfloat16 *Xh = P0h, *Xl = P0l, *Ah = P1h, *Al = P1l, *Bh = P2h, *Bl = P2l;
    for (int it = 0; it < 5; ++it) {
      // A = XT * XT^T (symmetric, 10 upper tiles): hi*hi + hi*lo + lo*hi
      k_gemm<1><<<dim3(CH * 10), 512, 0, stream>>>(XTh, XTh, XTl, XTh, XTl, XTh,
                                                   Ah, Al, Ah, Al, nullptr,
                                                   nullptr, nullptr, nullptr);
      // B = c2*A^2 + c1*A + c0*I (symmetric, 10 upper tiles)
      k_gemm<2><<<dim3(CH * 10), 512, 0, stream>>>(Ah, Ah, Al, Ah, Al, Ah,
                                                   Bh, Bl, Bh, Bl, nullptr,
                                                   Ah, Al, coef);
      // X_next = X * B^T (B symmetric); coalesced splits -> dead A pair;
      // XT splits fused via LDS transpose (it<4); fp32 out on last iter.
      k_gemm<3><<<dim3(CH * 16), 512, 0, stream>>>(Xh, Xh, Xl, Bh, Bl, Bh,
                                                   (it < 4) ? Ah : nullptr,
                                                   (it < 4) ? Al : nullptr,
                                                   (it < 4) ? XTh : nullptr,
                                                   (it < 4) ? XTl : nullptr,
                                                   (it == 4) ? X : nullptr,
                                                   nullptr, nullptr, nullptr);
      // rotate (X, A, B) <- (A, B, X)
      __hip_bfloat16 *th = Xh, *tl = Xl;
      Xh = Ah; Xl = Al;
      Ah = Bh; Al = Bl;
      Bh = th; Bl = tl;
    }
  }
}

// Round 15
// 7381.077 us; speedup vs baseline: 3.7587x; 1.0218x over previous
//
#include <hip/hip_runtime.h>
#include <hip/hip_bf16.h>
#include <stdint.h>

typedef float f32x4 __attribute__((ext_vector_type(4)));
typedef short bf16x8 __attribute__((ext_vector_type(8)));

#define LDW 1024
#define BATCH_SH 20  // 1<<20 elements per 1024x1024 matrix

__device__ __forceinline__ float b2f(__hip_bfloat16 h) { return __bfloat162float(h); }
__device__ __forceinline__ __hip_bfloat16 f2b(float f) { return __float2bfloat16(f); }

__device__ __forceinline__ void gload16(const void* g, void* l) {
  __builtin_amdgcn_global_load_lds((const __attribute__((address_space(1))) void*)g,
                                   (__attribute__((address_space(3))) void*)l,
                                   16, 0, 0);
}

// ---------------- Frobenius norm partials ----------------
__global__ void k_partial(const float* __restrict__ xin, float* __restrict__ partials) {
  const int b = blockIdx.y, ch = blockIdx.x, t = threadIdx.x;
  const size_t base = ((size_t)b << BATCH_SH) + (size_t)ch * 16384;
  float s = 0.f;
#pragma unroll
  for (int i = 0; i < 16; ++i) {
    f32x4 v = *reinterpret_cast<const f32x4*>(xin + base + (size_t)(i * 256 + t) * 4);
    s += v[0] * v[0] + v[1] * v[1] + v[2] * v[2] + v[3] * v[3];
  }
#pragma unroll
  for (int off = 32; off; off >>= 1) s += __shfl_down(s, off);
  __shared__ float red[4];
  if ((t & 63) == 0) red[t >> 6] = s;
  __syncthreads();
  if (t == 0) partials[b * 64 + ch] = red[0] + red[1] + red[2] + red[3];
}

// ---------------- scale + split + transpose-split (scale folded in) ----------------
__global__ void k_scalesplit(const float* __restrict__ xin, const float* __restrict__ partials,
                             __hip_bfloat16* __restrict__ Xh, __hip_bfloat16* __restrict__ Xl,
                             __hip_bfloat16* __restrict__ XTh, __hip_bfloat16* __restrict__ XTl) {
  __shared__ float tile[64][65];
  const int b = blockIdx.z, tm = blockIdx.y, tn = blockIdx.x;
  const size_t boff = (size_t)b << BATCH_SH;
  const int t = threadIdx.x, lr0 = t >> 6, lc = t & 63;
  float q = partials[b * 64 + (t & 63)];
#pragma unroll
  for (int off = 32; off; off >>= 1) q += __shfl_down(q, off);
  q = __shfl(q, 0);
  const float s = 1.1f / sqrtf(q);
#pragma unroll
  for (int p = 0; p < 16; ++p) {
    const int lr = p * 4 + lr0;
    const size_t idx = boff + (size_t)(tm * 64 + lr) * LDW + tn * 64 + lc;
    const float v = xin[idx] * s;
    __hip_bfloat16 h = f2b(v);
    Xh[idx] = h;
    Xl[idx] = f2b(v - b2f(h));
    tile[lr][lc] = v;
  }
  __syncthreads();
#pragma unroll
  for (int p = 0; p < 16; ++p) {
    const int lr = p * 4 + lr0;
    const float v = tile[lc][lr];
    const size_t idx = boff + (size_t)(tn * 64 + lr) * LDW + tm * 64 + lc;
    __hip_bfloat16 h = f2b(v);
    XTh[idx] = h;
    XTl[idx] = f2b(v - b2f(h));
  }
}

// ---------------- split-bf16 GEMM: C = PA * PB^T, 256x256 tile, BK=64 ----------------
// Effective K = 3072 (3 bf16 segments). 512 threads = 8 waves (2M x 4N).
// NEW: pipelined-fragment 4-phase K-step (the m201 mechanism, correctly ported):
// phase p issues ds_reads for fragment-set p+1, then MFMAs set p (operands
// loaded LAST phase -> the lgkm wait before each cluster is already satisfied).
// Stage of tile s+1 spread over phases 0-1; vmcnt(0) at phase 3 (>=2 phases of
// latency cover); ONE barrier per step, crossed with zero outstanding reads of
// the to-be-overwritten buffer. Staging image / offsets / modes unchanged.
// MODE 1 (SYM):  C symmetric; 10 upper tiles; mirror-write when tm!=tn.
// MODE 2 (POLY): v = c2*C + c1*A + c0*I; mirrored like MODE 1.
// MODE 3 (XUP):  v = C; coalesced splits; fused LDS-transpose splits; fp32.

#define SEGPTRS(S)                                                                        \
  const int seg_ = (S) >> 4, k0_ = ((S) & 15) << 6;                                       \
  const __hip_bfloat16* pa_ = seg_ == 0 ? pa0 : seg_ == 1 ? pa1 : pa2;                    \
  const __hip_bfloat16* pb_ = seg_ == 0 ? pb0 : seg_ == 1 ? pb1 : pb2;

// lane l of wave w stages row r = it*64 + w*8 + (l>>3), global chunk ((l&7)^(l>>3)),
// into linear LDS slot (row base + l*16). Image: LDS[r][slot] = chunk slot^(r&7).
#define STAGE_GL_H(DB, S, H)                                                              \
  {                                                                                       \
    SEGPTRS(S)                                                                            \
    char* lb_ = smem + (DB) * 65536;                                                      \
    _Pragma("unroll") for (int it_ = (H) * 2; it_ < (H) * 2 + 2; ++it_) {                 \
      const int r_ = it_ * 64 + w * 8 + (l >> 3);                                         \
      const int kx_ = k0_ + (((l & 7) ^ (l >> 3)) << 3);                                  \
      gload16(pa_ + boff + (size_t)(rowA + r_) * LDW + kx_,                               \
              lb_ + (it_ * 64 + w * 8) * 128 + l * 16);                                   \
      gload16(pb_ + boff + (size_t)(rowB + r_) * LDW + kx_,                               \
              lb_ + 32768 + (it_ * 64 + w * 8) * 128 + l * 16);                           \
    }                                                                                     \
  }

#define STAGE_GL(DB, S) { STAGE_GL_H(DB, S, 0) STAGE_GL_H(DB, S, 1) }

// 16-MFMA cluster on fragment set (AV, BV); MH selects the acc row-half.
#define MFMA_CL(AV, BV, MH)                                                               \
  __builtin_amdgcn_s_setprio(1);                                                          \
  _Pragma("unroll") for (int mi_ = 0; mi_ < 4; ++mi_)                                     \
      _Pragma("unroll") for (int ni_ = 0; ni_ < 4; ++ni_)                                 \
          acc[(MH) * 4 + mi_][ni_] = __builtin_amdgcn_mfma_f32_16x16x32_bf16(             \
              AV[mi_], BV[ni_], acc[(MH) * 4 + mi_][ni_], 0, 0, 0);                       \
  __builtin_amdgcn_s_setprio(0);

#define SCB() __builtin_amdgcn_sched_barrier(0)
#define BAR() __builtin_amdgcn_s_barrier()
#define LDF(P) (*reinterpret_cast<const bf16x8*>(P))

template <int MODE>
__global__ __launch_bounds__(512, 2) void k_gemm(
    const __hip_bfloat16* __restrict__ pa0, const __hip_bfloat16* __restrict__ pa1,
    const __hip_bfloat16* __restrict__ pa2, const __hip_bfloat16* __restrict__ pb0,
    const __hip_bfloat16* __restrict__ pb1, const __hip_bfloat16* __restrict__ pb2,
    __hip_bfloat16* oh, __hip_bfloat16* ol,
    __hip_bfloat16* oth, __hip_bfloat16* otl,
    float* __restrict__ of,
    const __hip_bfloat16* __restrict__ eh, const __hip_bfloat16* __restrict__ el,
    const float* __restrict__ coef) {
  __shared__ __align__(16) char smem[131072];  // 2 bufs x (A 32KB + B 32KB)
  const int t = threadIdx.x;
  const int w = t >> 6, l = t & 63;
  const int wr = w >> 2, wc = w & 3;  // 2M x 4N wave grid

  // Fully-bijective XCD-aware swizzle (m204): works for any gridDim.x.
  const int nwg = gridDim.x, q = nwg >> 3, r8 = nwg & 7;
  const int xcd = blockIdx.x & 7, o = blockIdx.x >> 3;
  const int wgid = (xcd < r8 ? xcd * (q + 1) : r8 * (q + 1) + (xcd - r8) * q) + o;

  int bat, tm, tn;
  if constexpr (MODE == 3) {
    bat = wgid >> 4;
    const int tile = wgid & 15;
    tm = tile >> 2; tn = tile & 3;
  } else {
    bat = (int)((unsigned)wgid / 10u);
    const int tile = wgid - bat * 10;
    tm = (tile < 4) ? 0 : (tile < 7) ? 1 : (tile < 9) ? 2 : 3;
    tn = (tile < 4) ? tile : (tile < 7) ? (tile - 3) : (tile < 9) ? (tile - 5) : 3;
  }
  const size_t boff = (size_t)bat << BATCH_SH;
  const int rowA = tm * 256, rowB = tn * 256;

  f32x4 acc[8][4];
#pragma unroll
  for (int i = 0; i < 8; ++i)
#pragma unroll
    for (int j = 0; j < 4; ++j) acc[i][j] = (f32x4){0.f, 0.f, 0.f, 0.f};

  // MFMA fragment LDS byte offsets (within a buffer), XOR chunk swizzle
  int offA[2][8], offB[2][4];
#pragma unroll
  for (int kk = 0; kk < 2; ++kk) {
    const int g = kk * 4 + (l >> 4);
#pragma unroll
    for (int mi = 0; mi < 8; ++mi) {
      const int rA = wr * 128 + mi * 16 + (l & 15);
      offA[kk][mi] = rA * 128 + ((g ^ (rA & 7)) << 4);
    }
#pragma unroll
    for (int ni = 0; ni < 4; ++ni) {
      const int rB = wc * 64 + ni * 16 + (l & 15);
      offB[kk][ni] = 32768 + rB * 128 + ((g ^ (rB & 7)) << 4);
    }
  }

  // prologue: stage tile 0 -> buf0, drain, converge, preload set0 fragments
  STAGE_GL(0, 0);
  asm volatile("s_waitcnt vmcnt(0)" ::: "memory");
  SCB();
  BAR();
  SCB();

  bf16x8 avA[4], avB[4], bvA[4], bvB[4];
#pragma unroll
  for (int i = 0; i < 4; ++i) avA[i] = LDF(smem + offA[0][i]);
#pragma unroll
  for (int i = 0; i < 4; ++i) bvA[i] = LDF(smem + offB[0][i]);

  for (int s = 0; s < 48; ++s) {
    const int base = (s & 1) * 65536;
    const int nb = ((s & 1) ^ 1) * 65536;
    const bool pf = (s + 1 < 48);
    // phase 0: stage half 0 of tile s+1; read set1 (kk0,mh1); MFMA set0
    if (pf) STAGE_GL_H((s & 1) ^ 1, s + 1, 0);
#pragma unroll
    for (int i = 0; i < 4; ++i) avB[i] = LDF(smem + base + offA[0][4 + i]);
    SCB();
    MFMA_CL(avA, bvA, 0);
    // phase 1: stage half 1; read set2 (kk1,mh0) + bv[kk1]; MFMA set1
    if (pf) STAGE_GL_H((s & 1) ^ 1, s + 1, 1);
#pragma unroll
    for (int i = 0; i < 4; ++i) avA[i] = LDF(smem + base + offA[1][i]);
#pragma unroll
    for (int i = 0; i < 4; ++i) bvB[i] = LDF(smem + base + offB[1][i]);
    SCB();
    MFMA_CL(avB, bvA, 1);
    // phase 2: read set3 (kk1,mh1); MFMA set2
#pragma unroll
    for (int i = 0; i < 4; ++i) avB[i] = LDF(smem + base + offA[1][4 + i]);
    SCB();
    MFMA_CL(avA, bvB, 0);
    // phase 3: retire cur-buf reads; land tile s+1; barrier; read next set0; MFMA set3
    asm volatile("s_waitcnt lgkmcnt(0)" ::: "memory");  // set3 in regs; no cur-buf reads live
    SCB();
    if (pf) {
      asm volatile("s_waitcnt vmcnt(0)" ::: "memory");  // issued phases 0-1 -> cheap
      SCB();
    }
    BAR();  // WAR: buf[cur] may be overwritten next step; buf[cur^1] published
    SCB();
    if (pf) {
#pragma unroll
      for (int i = 0; i < 4; ++i) avA[i] = LDF(smem + nb + offA[0][i]);
#pragma unroll
      for (int i = 0; i < 4; ++i) bvA[i] = LDF(smem + nb + offB[0][i]);
    }
    SCB();
    MFMA_CL(avB, bvB, 1);  // covers next-set0 read latency
  }

  float c0 = 0.f, c1 = 0.f, c2 = 0.f;
  if constexpr (MODE == 2) { c0 = coef[0]; c1 = coef[1]; c2 = coef[2]; }
  const int r0 = tm * 256 + wr * 128 + ((l >> 4) << 2);
  const int cb = tn * 256 + wc * 64 + (l & 15);
#pragma unroll
  for (int mi = 0; mi < 8; ++mi) {
#pragma unroll
    for (int ni = 0; ni < 4; ++ni) {
      const int ccol = cb + ni * 16;
#pragma unroll
      for (int j = 0; j < 4; ++j) {
        const int rrow = r0 + mi * 16 + j;
        const size_t idx = boff + (size_t)rrow * LDW + ccol;
        float v = acc[mi][ni][j];
        if constexpr (MODE == 2)
          v = c2 * v + c1 * (b2f(eh[idx]) + b2f(el[idx])) + (rrow == ccol ? c0 : 0.f);
        __hip_bfloat16 h = f2b(v);
        __hip_bfloat16 lo = f2b(v - b2f(h));
        if constexpr (MODE == 3) {
          if (oh) { oh[idx] = h; ol[idx] = lo; }
          if (of) of[idx] = v;
        } else {
          oh[idx] = h; ol[idx] = lo;
          if (tm != tn) {
            const size_t tix = boff + (size_t)ccol * LDW + rrow;
            oth[tix] = h; otl[tix] = lo;
          }
        }
      }
    }
  }

  // ---- MODE 3 fused transpose: dead staging LDS = one 256x128 u32 half-tile ----
  if constexpr (MODE == 3) {
    if (oth) {
      unsigned* tlds = reinterpret_cast<unsigned*>(smem);
      unsigned short* pth = reinterpret_cast<unsigned short*>(oth);
      unsigned short* ptl = reinterpret_cast<unsigned short*>(otl);
#pragma unroll
      for (int h2 = 0; h2 < 2; ++h2) {
        __builtin_amdgcn_s_barrier();  // K-loop reads / previous half reads done
        if ((wc >> 1) == h2) {         // waves owning this 128-col half pack into LDS
#pragma unroll
          for (int mi = 0; mi < 8; ++mi) {
#pragma unroll
            for (int ni = 0; ni < 4; ++ni) {
              const int cl = (wc & 1) * 64 + ni * 16 + (l & 15);  // 0..127 in half
#pragma unroll
              for (int j = 0; j < 4; ++j) {
                const int rr = wr * 128 + ((l >> 4) << 2) + mi * 16 + j;  // 0..255
                const float v = acc[mi][ni][j];
                const __hip_bfloat16 hh = f2b(v);
                const __hip_bfloat16 lo = f2b(v - b2f(hh));
                const unsigned pk = (unsigned)(*(const unsigned short*)&hh) |
                                    ((unsigned)(*(const unsigned short*)&lo) << 16);
                tlds[rr * 128 + (cl ^ ((rr >> 1) & 31))] = pk;
              }
            }
          }
        }
        __builtin_amdgcn_s_barrier();
        // all 8 waves: emit 16 transposed rows each, u32-packed coalesced stores
#pragma unroll
        for (int i = 0; i < 16; ++i) {
          const int trow = w * 16 + i;  // 0..127 within this half
          const size_t obase =
              boff + (size_t)(tn * 256 + h2 * 128 + trow) * LDW + tm * 256;
#pragma unroll
          for (int c = 0; c < 2; ++c) {
            const int e0 = (c * 64 + l) * 2;  // even element index 0..254
            const int m = (e0 >> 1) & 31;     // same mask for e0 and e0+1
            const unsigned p0 = tlds[e0 * 128 + (trow ^ m)];
            const unsigned p1 = tlds[(e0 + 1) * 128 + (trow ^ m)];
            *reinterpret_cast<unsigned*>(pth + obase + e0) =
                (p0 & 0xffffu) | (p1 << 16);
            *reinterpret_cast<unsigned*>(ptl + obase + e0) =
                (p0 >> 16) | (p1 & 0xffff0000u);
          }
        }
      }
    }
  }
}

extern "C" void kernel_launch(void* const* d_in, const int* in_sizes, int n_in,
                              void* d_out, int out_size, void* d_ws, size_t ws_size,
                              hipStream_t stream) {
  (void)in_sizes; (void)n_in; (void)out_size;
  const float* xin = (const float*)d_in[0];
  const float* coef = (const float*)d_in[1];
  float* xout = (float*)d_out;

  // ws need: 8 bf16 buffers (4 pairs) x CH x 2MB = 16 MB/batch (+64KB slack)
  int CH = 64;
  while (CH > 1 && ((size_t)CH * 16u * 1024u * 1024u + 65536u) > ws_size) CH >>= 1;

  const size_t nE = (size_t)CH << BATCH_SH;
  __hip_bfloat16* P0h = (__hip_bfloat16*)d_ws;
  __hip_bfloat16* P0l = P0h + nE;
  __hip_bfloat16* P1h = P0l + nE;
  __hip_bfloat16* P1l = P1h + nE;
  __hip_bfloat16* P2h = P1l + nE;
  __hip_bfloat16* P2l = P2h + nE;
  __hip_bfloat16* XTh = P2l + nE;
  __hip_bfloat16* XTl = XTh + nE;
  float* partials = (float*)(XTl + nE);

  for (int c = 0; c < 64; c += CH) {
    const float* xi = xin + ((size_t)c << BATCH_SH);
    float* X = xout + ((size_t)c << BATCH_SH);  // final fp32 output only
    k_partial<<<dim3(64, CH), 256, 0, stream>>>(xi, partials);
    k_scalesplit<<<dim3(16, 16, CH), 256, 0, stream>>>(xi, partials, P0h, P0l, XTh, XTl);

    // rotating pairs: X, A, B  (X_next reuses the dead A pair each iteration)
    __hip_bfloat16 *Xh = P0h, *Xl = P0l, *Ah = P1h, *Al = P1l, *Bh = P2h, *Bl = P2l;
    for (int it = 0; it < 5; ++it) {
      // A = XT * XT^T (symmetric, 10 upper tiles): hi*hi + hi*lo + lo*hi
      k_gemm<1><<<dim3(CH * 10), 512, 0, stream>>>(XTh, XTh, XTl, XTh, XTl, XTh,
                                                   Ah, Al, Ah, Al, nullptr,
                                                   nullptr, nullptr, nullptr);
      // B = c2*A^2 + c1*A + c0*I (symmetric, 10 upper tiles)
      k_gemm<2><<<dim3(CH * 10), 512, 0, stream>>>(Ah, Ah, Al, Ah, Al, Ah,
                                                   Bh, Bl, Bh, Bl, nullptr,
                                                   Ah, Al, coef);
      // X_next = X * B^T (B symmetric); coalesced splits -> dead A pair;
      // XT splits fused via LDS transpose (it<4); fp32 out on last iter.
      k_gemm<3><<<dim3(CH * 16), 512, 0, stream>>>(Xh, Xh, Xl, Bh, Bl, Bh,
                                                   (it < 4) ? Ah : nullptr,
                                                   (it < 4) ? Al : nullptr,
                                                   (it < 4) ? XTh : nullptr,
                                                   (it < 4) ? XTl : nullptr,
                                                   (it == 4) ? X : nullptr,
                                                   nullptr, nullptr, nullptr);
      // rotate (X, A, B) <- (A, B, X)
      __hip_bfloat16 *th = Xh, *tl = Xl;
      Xh = Ah; Xl = Al;
      Ah = Bh; Al = Bl;
      Bh = th; Bl = tl;
    }
  }
}

// Round 16
// 6852.640 us; speedup vs baseline: 4.0485x; 1.0771x over previous
//
#include <hip/hip_runtime.h>
#include <hip/hip_bf16.h>
#include <stdint.h>

typedef float f32x4 __attribute__((ext_vector_type(4)));
typedef short bf16x8 __attribute__((ext_vector_type(8)));

#define LDW 1024
#define BATCH_SH 20  // 1<<20 elements per 1024x1024 matrix

__device__ __forceinline__ float b2f(__hip_bfloat16 h) { return __bfloat162float(h); }
__device__ __forceinline__ __hip_bfloat16 f2b(float f) { return __float2bfloat16(f); }

__device__ __forceinline__ void gload16(const void* g, void* l) {
  __builtin_amdgcn_global_load_lds((const __attribute__((address_space(1))) void*)g,
                                   (__attribute__((address_space(3))) void*)l,
                                   16, 0, 0);
}

// ---------------- Frobenius norm partials ----------------
__global__ void k_partial(const float* __restrict__ xin, float* __restrict__ partials) {
  const int b = blockIdx.y, ch = blockIdx.x, t = threadIdx.x;
  const size_t base = ((size_t)b << BATCH_SH) + (size_t)ch * 16384;
  float s = 0.f;
#pragma unroll
  for (int i = 0; i < 16; ++i) {
    f32x4 v = *reinterpret_cast<const f32x4*>(xin + base + (size_t)(i * 256 + t) * 4);
    s += v[0] * v[0] + v[1] * v[1] + v[2] * v[2] + v[3] * v[3];
  }
#pragma unroll
  for (int off = 32; off; off >>= 1) s += __shfl_down(s, off);
  __shared__ float red[4];
  if ((t & 63) == 0) red[t >> 6] = s;
  __syncthreads();
  if (t == 0) partials[b * 64 + ch] = red[0] + red[1] + red[2] + red[3];
}

// ---------------- scale + split + transpose-split (scale folded in) ----------------
__global__ void k_scalesplit(const float* __restrict__ xin, const float* __restrict__ partials,
                             __hip_bfloat16* __restrict__ Xh, __hip_bfloat16* __restrict__ Xl,
                             __hip_bfloat16* __restrict__ XTh, __hip_bfloat16* __restrict__ XTl) {
  __shared__ float tile[64][65];
  const int b = blockIdx.z, tm = blockIdx.y, tn = blockIdx.x;
  const size_t boff = (size_t)b << BATCH_SH;
  const int t = threadIdx.x, lr0 = t >> 6, lc = t & 63;
  float q = partials[b * 64 + (t & 63)];
#pragma unroll
  for (int off = 32; off; off >>= 1) q += __shfl_down(q, off);
  q = __shfl(q, 0);
  const float s = 1.1f / sqrtf(q);
#pragma unroll
  for (int p = 0; p < 16; ++p) {
    const int lr = p * 4 + lr0;
    const size_t idx = boff + (size_t)(tm * 64 + lr) * LDW + tn * 64 + lc;
    const float v = xin[idx] * s;
    __hip_bfloat16 h = f2b(v);
    Xh[idx] = h;
    Xl[idx] = f2b(v - b2f(h));
    tile[lr][lc] = v;
  }
  __syncthreads();
#pragma unroll
  for (int p = 0; p < 16; ++p) {
    const int lr = p * 4 + lr0;
    const float v = tile[lc][lr];
    const size_t idx = boff + (size_t)(tn * 64 + lr) * LDW + tm * 64 + lc;
    __hip_bfloat16 h = f2b(v);
    XTh[idx] = h;
    XTl[idx] = f2b(v - b2f(h));
  }
}

// ---------------- split-bf16 GEMM: C = PA * PB^T, 256x256 tile, BK=64 ----------------
// NSEG template param: number of bf16 K-segments (3 = full split hh+hl+lh;
// 2 = hh+hl, used for iterations 3,4 where NS-map amplification is <= ~3x and
// the dropped lo*hi term (~3e-5 stat.) is within the absmax budget).
// Schedule = round-15 pipelined-fragment 4-phase K-step, frozen.
// MODE 1 (SYM):  C symmetric; 10 upper tiles; mirror-write when tm!=tn.
// MODE 2 (POLY): v = c2*C + c1*A + c0*I; mirrored like MODE 1.
// MODE 3 (XUP):  v = C; coalesced splits; fused LDS-transpose splits; fp32.

#define SEGPTRS(S)                                                                        \
  const int seg_ = (S) >> 4, k0_ = ((S) & 15) << 6;                                       \
  const __hip_bfloat16* pa_ = seg_ == 0 ? pa0 : seg_ == 1 ? pa1 : pa2;                    \
  const __hip_bfloat16* pb_ = seg_ == 0 ? pb0 : seg_ == 1 ? pb1 : pb2;

// lane l of wave w stages row r = it*64 + w*8 + (l>>3), global chunk ((l&7)^(l>>3)),
// into linear LDS slot (row base + l*16). Image: LDS[r][slot] = chunk slot^(r&7).
#define STAGE_GL_H(DB, S, H)                                                              \
  {                                                                                       \
    SEGPTRS(S)                                                                            \
    char* lb_ = smem + (DB) * 65536;                                                      \
    _Pragma("unroll") for (int it_ = (H) * 2; it_ < (H) * 2 + 2; ++it_) {                 \
      const int r_ = it_ * 64 + w * 8 + (l >> 3);                                         \
      const int kx_ = k0_ + (((l & 7) ^ (l >> 3)) << 3);                                  \
      gload16(pa_ + boff + (size_t)(rowA + r_) * LDW + kx_,                               \
              lb_ + (it_ * 64 + w * 8) * 128 + l * 16);                                   \
      gload16(pb_ + boff + (size_t)(rowB + r_) * LDW + kx_,                               \
              lb_ + 32768 + (it_ * 64 + w * 8) * 128 + l * 16);                           \
    }                                                                                     \
  }

#define STAGE_GL(DB, S) { STAGE_GL_H(DB, S, 0) STAGE_GL_H(DB, S, 1) }

// 16-MFMA cluster on fragment set (AV, BV); MH selects the acc row-half.
#define MFMA_CL(AV, BV, MH)                                                               \
  __builtin_amdgcn_s_setprio(1);                                                          \
  _Pragma("unroll") for (int mi_ = 0; mi_ < 4; ++mi_)                                     \
      _Pragma("unroll") for (int ni_ = 0; ni_ < 4; ++ni_)                                 \
          acc[(MH) * 4 + mi_][ni_] = __builtin_amdgcn_mfma_f32_16x16x32_bf16(             \
              AV[mi_], BV[ni_], acc[(MH) * 4 + mi_][ni_], 0, 0, 0);                       \
  __builtin_amdgcn_s_setprio(0);

#define SCB() __builtin_amdgcn_sched_barrier(0)
#define BAR() __builtin_amdgcn_s_barrier()
#define LDF(P) (*reinterpret_cast<const bf16x8*>(P))

template <int MODE, int NSEG>
__global__ __launch_bounds__(512, 2) void k_gemm(
    const __hip_bfloat16* __restrict__ pa0, const __hip_bfloat16* __restrict__ pa1,
    const __hip_bfloat16* __restrict__ pa2, const __hip_bfloat16* __restrict__ pb0,
    const __hip_bfloat16* __restrict__ pb1, const __hip_bfloat16* __restrict__ pb2,
    __hip_bfloat16* oh, __hip_bfloat16* ol,
    __hip_bfloat16* oth, __hip_bfloat16* otl,
    float* __restrict__ of,
    const __hip_bfloat16* __restrict__ eh, const __hip_bfloat16* __restrict__ el,
    const float* __restrict__ coef) {
  constexpr int NS = NSEG * 16;  // K-steps
  __shared__ __align__(16) char smem[131072];  // 2 bufs x (A 32KB + B 32KB)
  const int t = threadIdx.x;
  const int w = t >> 6, l = t & 63;
  const int wr = w >> 2, wc = w & 3;  // 2M x 4N wave grid

  // Fully-bijective XCD-aware swizzle (m204): works for any gridDim.x.
  const int nwg = gridDim.x, q = nwg >> 3, r8 = nwg & 7;
  const int xcd = blockIdx.x & 7, o = blockIdx.x >> 3;
  const int wgid = (xcd < r8 ? xcd * (q + 1) : r8 * (q + 1) + (xcd - r8) * q) + o;

  int bat, tm, tn;
  if constexpr (MODE == 3) {
    bat = wgid >> 4;
    const int tile = wgid & 15;
    tm = tile >> 2; tn = tile & 3;
  } else {
    bat = (int)((unsigned)wgid / 10u);
    const int tile = wgid - bat * 10;
    tm = (tile < 4) ? 0 : (tile < 7) ? 1 : (tile < 9) ? 2 : 3;
    tn = (tile < 4) ? tile : (tile < 7) ? (tile - 3) : (tile < 9) ? (tile - 5) : 3;
  }
  const size_t boff = (size_t)bat << BATCH_SH;
  const int rowA = tm * 256, rowB = tn * 256;

  f32x4 acc[8][4];
#pragma unroll
  for (int i = 0; i < 8; ++i)
#pragma unroll
    for (int j = 0; j < 4; ++j) acc[i][j] = (f32x4){0.f, 0.f, 0.f, 0.f};

  // MFMA fragment LDS byte offsets (within a buffer), XOR chunk swizzle
  int offA[2][8], offB[2][4];
#pragma unroll
  for (int kk = 0; kk < 2; ++kk) {
    const int g = kk * 4 + (l >> 4);
#pragma unroll
    for (int mi = 0; mi < 8; ++mi) {
      const int rA = wr * 128 + mi * 16 + (l & 15);
      offA[kk][mi] = rA * 128 + ((g ^ (rA & 7)) << 4);
    }
#pragma unroll
    for (int ni = 0; ni < 4; ++ni) {
      const int rB = wc * 64 + ni * 16 + (l & 15);
      offB[kk][ni] = 32768 + rB * 128 + ((g ^ (rB & 7)) << 4);
    }
  }

  // prologue: stage tile 0 -> buf0, drain, converge, preload set0 fragments
  STAGE_GL(0, 0);
  asm volatile("s_waitcnt vmcnt(0)" ::: "memory");
  SCB();
  BAR();
  SCB();

  bf16x8 avA[4], avB[4], bvA[4], bvB[4];
#pragma unroll
  for (int i = 0; i < 4; ++i) avA[i] = LDF(smem + offA[0][i]);
#pragma unroll
  for (int i = 0; i < 4; ++i) bvA[i] = LDF(smem + offB[0][i]);

  for (int s = 0; s < NS; ++s) {
    const int base = (s & 1) * 65536;
    const int nb = ((s & 1) ^ 1) * 65536;
    const bool pf = (s + 1 < NS);
    // phase 0: stage half 0 of tile s+1; read set1 (kk0,mh1); MFMA set0
    if (pf) STAGE_GL_H((s & 1) ^ 1, s + 1, 0);
#pragma unroll
    for (int i = 0; i < 4; ++i) avB[i] = LDF(smem + base + offA[0][4 + i]);
    SCB();
    MFMA_CL(avA, bvA, 0);
    // phase 1: stage half 1; read set2 (kk1,mh0) + bv[kk1]; MFMA set1
    if (pf) STAGE_GL_H((s & 1) ^ 1, s + 1, 1);
#pragma unroll
    for (int i = 0; i < 4; ++i) avA[i] = LDF(smem + base + offA[1][i]);
#pragma unroll
    for (int i = 0; i < 4; ++i) bvB[i] = LDF(smem + base + offB[1][i]);
    SCB();
    MFMA_CL(avB, bvA, 1);
    // phase 2: read set3 (kk1,mh1); MFMA set2
#pragma unroll
    for (int i = 0; i < 4; ++i) avB[i] = LDF(smem + base + offA[1][4 + i]);
    SCB();
    MFMA_CL(avA, bvB, 0);
    // phase 3: retire cur-buf reads; land tile s+1; barrier; read next set0; MFMA set3
    asm volatile("s_waitcnt lgkmcnt(0)" ::: "memory");  // set3 in regs; no cur-buf reads live
    SCB();
    if (pf) {
      asm volatile("s_waitcnt vmcnt(0)" ::: "memory");  // issued phases 0-1 -> cheap
      SCB();
    }
    BAR();  // WAR: buf[cur] may be overwritten next step; buf[cur^1] published
    SCB();
    if (pf) {
#pragma unroll
      for (int i = 0; i < 4; ++i) avA[i] = LDF(smem + nb + offA[0][i]);
#pragma unroll
      for (int i = 0; i < 4; ++i) bvA[i] = LDF(smem + nb + offB[0][i]);
    }
    SCB();
    MFMA_CL(avB, bvB, 1);  // covers next-set0 read latency
  }

  float c0 = 0.f, c1 = 0.f, c2 = 0.f;
  if constexpr (MODE == 2) { c0 = coef[0]; c1 = coef[1]; c2 = coef[2]; }
  const int r0 = tm * 256 + wr * 128 + ((l >> 4) << 2);
  const int cb = tn * 256 + wc * 64 + (l & 15);
#pragma unroll
  for (int mi = 0; mi < 8; ++mi) {
#pragma unroll
    for (int ni = 0; ni < 4; ++ni) {
      const int ccol = cb + ni * 16;
#pragma unroll
      for (int j = 0; j < 4; ++j) {
        const int rrow = r0 + mi * 16 + j;
        const size_t idx = boff + (size_t)rrow * LDW + ccol;
        float v = acc[mi][ni][j];
        if constexpr (MODE == 2)
          v = c2 * v + c1 * (b2f(eh[idx]) + b2f(el[idx])) + (rrow == ccol ? c0 : 0.f);
        __hip_bfloat16 h = f2b(v);
        __hip_bfloat16 lo = f2b(v - b2f(h));
        if constexpr (MODE == 3) {
          if (oh) { oh[idx] = h; ol[idx] = lo; }
          if (of) of[idx] = v;
        } else {
          oh[idx] = h; ol[idx] = lo;
          if (tm != tn) {
            const size_t tix = boff + (size_t)ccol * LDW + rrow;
            oth[tix] = h; otl[tix] = lo;
          }
        }
      }
    }
  }

  // ---- MODE 3 fused transpose: dead staging LDS = one 256x128 u32 half-tile ----
  if constexpr (MODE == 3) {
    if (oth) {
      unsigned* tlds = reinterpret_cast<unsigned*>(smem);
      unsigned short* pth = reinterpret_cast<unsigned short*>(oth);
      unsigned short* ptl = reinterpret_cast<unsigned short*>(otl);
#pragma unroll
      for (int h2 = 0; h2 < 2; ++h2) {
        __builtin_amdgcn_s_barrier();  // K-loop reads / previous half reads done
        if ((wc >> 1) == h2) {         // waves owning this 128-col half pack into LDS
#pragma unroll
          for (int mi = 0; mi < 8; ++mi) {
#pragma unroll
            for (int ni = 0; ni < 4; ++ni) {
              const int cl = (wc & 1) * 64 + ni * 16 + (l & 15);  // 0..127 in half
#pragma unroll
              for (int j = 0; j < 4; ++j) {
                const int rr = wr * 128 + ((l >> 4) << 2) + mi * 16 + j;  // 0..255
                const float v = acc[mi][ni][j];
                const __hip_bfloat16 hh = f2b(v);
                const __hip_bfloat16 lo = f2b(v - b2f(hh));
                const unsigned pk = (unsigned)(*(const unsigned short*)&hh) |
                                    ((unsigned)(*(const unsigned short*)&lo) << 16);
                tlds[rr * 128 + (cl ^ ((rr >> 1) & 31))] = pk;
              }
            }
          }
        }
        __builtin_amdgcn_s_barrier();
        // all 8 waves: emit 16 transposed rows each, u32-packed coalesced stores
#pragma unroll
        for (int i = 0; i < 16; ++i) {
          const int trow = w * 16 + i;  // 0..127 within this half
          const size_t obase =
              boff + (size_t)(tn * 256 + h2 * 128 + trow) * LDW + tm * 256;
#pragma unroll
          for (int c = 0; c < 2; ++c) {
            const int e0 = (c * 64 + l) * 2;  // even element index 0..254
            const int m = (e0 >> 1) & 31;     // same mask for e0 and e0+1
            const unsigned p0 = tlds[e0 * 128 + (trow ^ m)];
            const unsigned p1 = tlds[(e0 + 1) * 128 + (trow ^ m)];
            *reinterpret_cast<unsigned*>(pth + obase + e0) =
                (p0 & 0xffffu) | (p1 << 16);
            *reinterpret_cast<unsigned*>(ptl + obase + e0) =
                (p0 >> 16) | (p1 & 0xffff0000u);
          }
        }
      }
    }
  }
}

extern "C" void kernel_launch(void* const* d_in, const int* in_sizes, int n_in,
                              void* d_out, int out_size, void* d_ws, size_t ws_size,
                              hipStream_t stream) {
  (void)in_sizes; (void)n_in; (void)out_size;
  const float* xin = (const float*)d_in[0];
  const float* coef = (const float*)d_in[1];
  float* xout = (float*)d_out;

  // ws need: 8 bf16 buffers (4 pairs) x CH x 2MB = 16 MB/batch (+64KB slack)
  int CH = 64;
  while (CH > 1 && ((size_t)CH * 16u * 1024u * 1024u + 65536u) > ws_size) CH >>= 1;

  const size_t nE = (size_t)CH << BATCH_SH;
  __hip_bfloat16* P0h = (__hip_bfloat16*)d_ws;
  __hip_bfloat16* P0l = P0h + nE;
  __hip_bfloat16* P1h = P0l + nE;
  __hip_bfloat16* P1l = P1h + nE;
  __hip_bfloat16* P2h = P1l + nE;
  __hip_bfloat16* P2l = P2h + nE;
  __hip_bfloat16* XTh = P2l + nE;
  __hip_bfloat16* XTl = XTh + nE;
  float* partials = (float*)(XTl + nE);

  for (int c = 0; c < 64; c += CH) {
    const float* xi = xin + ((size_t)c << BATCH_SH);
    float* X = xout + ((size_t)c << BATCH_SH);  // final fp32 output only
    k_partial<<<dim3(64, CH), 256, 0, stream>>>(xi, partials);
    k_scalesplit<<<dim3(16, 16, CH), 256, 0, stream>>>(xi, partials, P0h, P0l, XTh, XTl);

    // rotating pairs: X, A, B  (X_next reuses the dead A pair each iteration)
    __hip_bfloat16 *Xh = P0h, *Xl = P0l, *Ah = P1h, *Al = P1l, *Bh = P2h, *Bl = P2l;
    for (int it = 0; it < 5; ++it) {
      const bool full = (it < 3);  // iters 3,4: 2-segment (error amp <= ~3x)
      // A = XT * XT^T (symmetric, 10 upper tiles)
      if (full)
        k_gemm<1, 3><<<dim3(CH * 10), 512, 0, stream>>>(XTh, XTh, XTl, XTh, XTl, XTh,
                                                        Ah, Al, Ah, Al, nullptr,
                                                        nullptr, nullptr, nullptr);
      else
        k_gemm<1, 2><<<dim3(CH * 10), 512, 0, stream>>>(XTh, XTh, XTl, XTh, XTl, XTh,
                                                        Ah, Al, Ah, Al, nullptr,
                                                        nullptr, nullptr, nullptr);
      // B = c2*A^2 + c1*A + c0*I (symmetric, 10 upper tiles)
      if (full)
        k_gemm<2, 3><<<dim3(CH * 10), 512, 0, stream>>>(Ah, Ah, Al, Ah, Al, Ah,
                                                        Bh, Bl, Bh, Bl, nullptr,
                                                        Ah, Al, coef);
      else
        k_gemm<2, 2><<<dim3(CH * 10), 512, 0, stream>>>(Ah, Ah, Al, Ah, Al, Ah,
                                                        Bh, Bl, Bh, Bl, nullptr,
                                                        Ah, Al, coef);
      // X_next = X * B^T (B symmetric); coalesced splits -> dead A pair;
      // XT splits fused via LDS transpose (it<4); fp32 out on last iter.
      if (full)
        k_gemm<3, 3><<<dim3(CH * 16), 512, 0, stream>>>(Xh, Xh, Xl, Bh, Bl, Bh,
                                                        (it < 4) ? Ah : nullptr,
                                                        (it < 4) ? Al : nullptr,
                                                        (it < 4) ? XTh : nullptr,
                                                        (it < 4) ? XTl : nullptr,
                                                        (it == 4) ? X : nullptr,
                                                        nullptr, nullptr, nullptr);
      else
        k_gemm<3, 2><<<dim3(CH * 16), 512, 0, stream>>>(Xh, Xh, Xl, Bh, Bl, Bh,
                                                        (it < 4) ? Ah : nullptr,
                                                        (it < 4) ? Al : nullptr,
                                                        (it < 4) ? XTh : nullptr,
                                                        (it < 4) ? XTl : nullptr,
                                                        (it == 4) ? X : nullptr,
                                                        nullptr, nullptr, nullptr);
      // rotate (X, A, B) <- (A, B, X)
      __hip_bfloat16 *th = Xh, *tl = Xl;
      Xh = Ah; Xl = Al;
      Ah = Bh; Al = Bl;
      Bh = th; Bl = tl;
    }
  }
}